// Round 13
// baseline (112.644 us; speedup 1.0000x reference)
//
#include <hip/hip_runtime.h>
#include <hip/hip_bf16.h>

// Problem constants (match reference)
#define BATCH 4096
#define NC    1024   // n_concepts (K)
#define NL    512    // n_lemmas   (N)
#define TSTEPS 50
#define GAMMA_C 0.95f
#define KAPPA_C 0.1f
#define FLOOR_C 1e-6f

typedef __attribute__((ext_vector_type(8))) short short8;  // 8 bf16 = 4 VGPRs
typedef __attribute__((ext_vector_type(4))) float f32x4;   // MFMA C/D frag

// ---------------- split fp32 -> bf16 hi + bf16 lo (RNE both) ----------------
__device__ inline void split_bf16(float x, unsigned short& h, unsigned short& l) {
    unsigned u = __float_as_uint(x);
    unsigned rh = u + 0x7FFFu + ((u >> 16) & 1u);
    h = (unsigned short)(rh >> 16);
    float hf = __uint_as_float((unsigned)h << 16);
    float r = x - hf;
    unsigned v = __float_as_uint(r);
    unsigned rl = v + 0x7FFFu + ((v >> 16) & 1u);
    l = (unsigned short)(rl >> 16);
}

// packed split via v_cvt_pk_bf16_f32 (RNE): ~3 VALU/elem vs ~9 scalar
__device__ __forceinline__ void split2_pk(float x0, float x1,
                                          unsigned& hp, unsigned& lp) {
    union { __hip_bfloat162 b; unsigned u; } ch, cl;
    ch.b = __float22bfloat162_rn(make_float2(x0, x1));
    hp = ch.u;
    const float hf0 = __uint_as_float(hp << 16);
    const float hf1 = __uint_as_float(hp & 0xFFFF0000u);
    cl.b = __float22bfloat162_rn(make_float2(x0 - hf0, x1 - hf1));
    lp = cl.u;
}

// W-only conversion: 512x1024 floats -> hi/lo bf16
__global__ __launch_bounds__(256)
void convert_w(const float* __restrict__ W,
               unsigned short* __restrict__ Whi, unsigned short* __restrict__ Wlo) {
    const int fidx = (blockIdx.x * 256 + threadIdx.x) * 4;
    const float4 v = *(const float4*)(W + fidx);
    ushort4 h4, l4;
    split_bf16(v.x, h4.x, l4.x);
    split_bf16(v.y, h4.y, l4.y);
    split_bf16(v.z, h4.z, l4.z);
    split_bf16(v.w, h4.w, l4.w);
    *(ushort4*)(Whi + fidx) = h4;
    *(ushort4*)(Wlo + fidx) = l4;
}

// ------- full-wave (64-lane) sum, broadcast to all lanes, via DPP ----------
__device__ __forceinline__ float wave_sum_bcast(float x) {
    float f = x;
    f += __int_as_float(__builtin_amdgcn_update_dpp(
            0, __float_as_int(f), 0x111, 0xf, 0xf, true));   // row_shr:1
    f += __int_as_float(__builtin_amdgcn_update_dpp(
            0, __float_as_int(f), 0x112, 0xf, 0xf, true));   // row_shr:2
    f += __int_as_float(__builtin_amdgcn_update_dpp(
            0, __float_as_int(f), 0x114, 0xf, 0xf, true));   // row_shr:4
    f += __int_as_float(__builtin_amdgcn_update_dpp(
            0, __float_as_int(f), 0x118, 0xf, 0xf, true));   // row_shr:8
    f += __int_as_float(__builtin_amdgcn_update_dpp(
            0, __float_as_int(f), 0x142, 0xa, 0xf, true));   // row_bcast:15
    f += __int_as_float(__builtin_amdgcn_update_dpp(
            0, __float_as_int(f), 0x143, 0xc, 0xf, true));   // row_bcast:31
    return __int_as_float(__builtin_amdgcn_readlane(__float_as_int(f), 63));
}

// ------------- MFMA GEMM: D = Ahi*Whi^T + Ahi*Wlo^T + Alo*Whi^T -------------
// B (W hi/lo) is NOT staged through LDS: each wave loads its B fragments
// directly from global (16 B/lane global_load_dwordx4; W is 4.2 MB, hot in
// L2; 16 rows/site share one 64 B line per stage). Only A goes through LDS
// (12 KB commit/block vs 48 KB before) -> barrier-coupled work shrinks 4x,
// LDS 20 KB. Block 128x128, 256 thr = 4 waves (2Mx2N), wave-tile 64x64,
// GK=32, splitK=4 -> grid (32,4,4) = 512 blocks.
#define TM 128
#define TN 128
#define GK 32
#define LDT 40

__global__ __launch_bounds__(256)
void gemm_bf16x2(const float* __restrict__ A,
                 const unsigned short* __restrict__ Whi, const unsigned short* __restrict__ Wlo,
                 float* __restrict__ Dp, int kPerSplit) {
    __shared__ unsigned short AsH[TM * LDT];   // 10 KB
    __shared__ unsigned short AsL[TM * LDT];   // 10 KB

    const int tid = threadIdx.x;
    const int m0 = blockIdx.x * TM;
    const int n0 = blockIdx.y * TN;
    const int kb = blockIdx.z * kPerSplit;

    // A staging: thread t owns row t>>1 (0..127), k-off (t&1)*16, 16 floats
    const int sr0 = tid >> 1;
    const int kc0 = (tid & 1) * 16;
    const float* gA = A + (size_t)(m0 + sr0) * NC + kb + kc0;

    unsigned short* wAh = AsH + sr0 * LDT + kc0;
    unsigned short* wAl = AsL + sr0 * LDT + kc0;

    // wave layout: 2(M) x 2(N), wave-tile 64x64
    const int lane = tid & 63;
    const int w    = tid >> 6;
    const int mw   = (w >> 1) * 64;
    const int nw   = (w & 1) * 64;
    const int sr   = lane & 15;
    const int quad = lane >> 4;

    const unsigned short* rAh = AsH + (mw + sr) * LDT + quad * 8;
    const unsigned short* rAl = AsL + (mw + sr) * LDT + quad * 8;

    // B fragment pointers: lane holds W[n0+nw+ni*16+sr][kb+kt+quad*8 ..+8]
    const size_t boff = (size_t)(n0 + nw + sr) * NC + kb + quad * 8;
    const unsigned short* gBh = Whi + boff;
    const unsigned short* gBl = Wlo + boff;

    f32x4 acc[4][4];
    #pragma unroll
    for (int i = 0; i < 4; ++i)
        #pragma unroll
        for (int j = 0; j < 4; ++j)
            acc[i][j] = (f32x4){0.f, 0.f, 0.f, 0.f};

    float4 pA0 = *(const float4*)gA;
    float4 pA1 = *(const float4*)(gA + 4);
    float4 pA2 = *(const float4*)(gA + 8);
    float4 pA3 = *(const float4*)(gA + 12);

    for (int kt = 0; kt < kPerSplit; kt += GK) {
        // ---- pk-split staged fp32 A to hi/lo, commit to LDS (12 KB/block)
        {
            unsigned h[8], l[8];
            split2_pk(pA0.x, pA0.y, h[0], l[0]);
            split2_pk(pA0.z, pA0.w, h[1], l[1]);
            split2_pk(pA1.x, pA1.y, h[2], l[2]);
            split2_pk(pA1.z, pA1.w, h[3], l[3]);
            split2_pk(pA2.x, pA2.y, h[4], l[4]);
            split2_pk(pA2.z, pA2.w, h[5], l[5]);
            split2_pk(pA3.x, pA3.y, h[6], l[6]);
            split2_pk(pA3.z, pA3.w, h[7], l[7]);
            uint4 hv0; hv0.x = h[0]; hv0.y = h[1]; hv0.z = h[2]; hv0.w = h[3];
            uint4 hv1; hv1.x = h[4]; hv1.y = h[5]; hv1.z = h[6]; hv1.w = h[7];
            uint4 lv0; lv0.x = l[0]; lv0.y = l[1]; lv0.z = l[2]; lv0.w = l[3];
            uint4 lv1; lv1.x = l[4]; lv1.y = l[5]; lv1.z = l[6]; lv1.w = l[7];
            *(uint4*)wAh       = hv0;
            *(uint4*)(wAh + 8) = hv1;
            *(uint4*)wAl       = lv0;
            *(uint4*)(wAl + 8) = lv1;
        }
        __syncthreads();

        // ---- prefetch next A stage (regs); no wrap loads on last stage
        const bool more = (kt + GK < kPerSplit);
        if (more) {
            const int kn = kt + GK;
            pA0 = *(const float4*)(gA + kn);
            pA1 = *(const float4*)(gA + kn + 4);
            pA2 = *(const float4*)(gA + kn + 8);
            pA3 = *(const float4*)(gA + kn + 12);
        }

        // ---- B fragments straight from global (L2-hot, no barrier coupling)
        short8 bfh[4], bfl[4];
        #pragma unroll
        for (int ni = 0; ni < 4; ++ni) {
            bfh[ni] = *(const short8*)(gBh + (size_t)ni * 16 * NC + kt);
            bfl[ni] = *(const short8*)(gBl + (size_t)ni * 16 * NC + kt);
        }

        // ---- A fragments from LDS
        short8 afh[4], afl[4];
        #pragma unroll
        for (int mi = 0; mi < 4; ++mi) {
            afh[mi] = *(const short8*)(rAh + mi * 16 * LDT);
            afl[mi] = *(const short8*)(rAl + mi * 16 * LDT);
        }

        // 48 MFMAs: 16 sites x (hi*hi + hi*lo + lo*hi)
        #pragma unroll
        for (int mi = 0; mi < 4; ++mi) {
            #pragma unroll
            for (int ni = 0; ni < 4; ++ni) {
                acc[mi][ni] = __builtin_amdgcn_mfma_f32_16x16x32_bf16(
                    afh[mi], bfh[ni], acc[mi][ni], 0, 0, 0);
                acc[mi][ni] = __builtin_amdgcn_mfma_f32_16x16x32_bf16(
                    afh[mi], bfl[ni], acc[mi][ni], 0, 0, 0);
                acc[mi][ni] = __builtin_amdgcn_mfma_f32_16x16x32_bf16(
                    afl[mi], bfh[ni], acc[mi][ni], 0, 0, 0);
            }
        }
        __syncthreads();
    }

    // epilogue: C/D layout col = lane&15, row = quad*4 + reg  [m89/m91]
    float* Dz = Dp + (size_t)blockIdx.z * BATCH * NL;
    #pragma unroll
    for (int mi = 0; mi < 4; ++mi) {
        #pragma unroll
        for (int ni = 0; ni < 4; ++ni) {
            const int col = n0 + nw + ni * 16 + sr;
            #pragma unroll
            for (int r = 0; r < 4; ++r) {
                const int row = m0 + mw + mi * 16 + quad * 4 + r;
                Dz[(size_t)row * NL + col] = acc[mi][ni][r];
            }
        }
    }
}

// ------ 50-step recurrence + selection: 64 lanes per row, 8 cols/lane -------
template<int SK>
__global__ __launch_bounds__(256)
void iterate_select(const float* __restrict__ Dp,
                    float* __restrict__ a_out,
                    float* __restrict__ sel_out, float* __restrict__ conf_out) {
    const int lane = threadIdx.x & 63;
    const int wave = threadIdx.x >> 6;
    const int row  = blockIdx.x * 4 + wave;

    float d[8];
    {
        float4 v[SK][2];
        #pragma unroll
        for (int s = 0; s < SK; ++s) {
            const float4* ps = (const float4*)(Dp + (size_t)s * BATCH * NL
                                               + (size_t)row * NL + lane * 8);
            v[s][0] = ps[0];
            v[s][1] = ps[1];
        }
        d[0] = v[0][0].x; d[1] = v[0][0].y; d[2] = v[0][0].z; d[3] = v[0][0].w;
        d[4] = v[0][1].x; d[5] = v[0][1].y; d[6] = v[0][1].z; d[7] = v[0][1].w;
        #pragma unroll
        for (int s = 1; s < SK; ++s) {
            d[0] += v[s][0].x; d[1] += v[s][0].y; d[2] += v[s][0].z; d[3] += v[s][0].w;
            d[4] += v[s][1].x; d[5] += v[s][1].y; d[6] += v[s][1].z; d[7] += v[s][1].w;
        }
    }

    float a[8];
    #pragma unroll
    for (int j = 0; j < 8; ++j) a[j] = 0.f;

    const float K1 = 1.0f + KAPPA_C;

    for (int t = 0; t < TSTEPS; ++t) {
        #pragma unroll
        for (int j = 0; j < 8; ++j) a[j] = fmaf(GAMMA_C, a[j], d[j]);

        float t4a = a[0] + a[4], t4b = a[1] + a[5], t4c = a[2] + a[6], t4d = a[3] + a[7];
        float t2a = t4a + t4c, t2b = t4b + t4d;
        const float S = wave_sum_bcast(t2a + t2b);

        const float h = -KAPPA_C * S;
        #pragma unroll
        for (int j = 0; j < 8; ++j) {
            const float v = fmaf(K1, a[j], h);
            a[j] = v > 0.f ? v : 0.f;
        }
    }

    // ---- epilogue (runs once): peak, sum, confidence, first-index argmax ----
    float m4a = fmaxf(a[0], a[4]), m4b = fmaxf(a[1], a[5]);
    float m4c = fmaxf(a[2], a[6]), m4d = fmaxf(a[3], a[7]);
    float peak = fmaxf(fmaxf(m4a, m4b), fmaxf(m4c, m4d));
    float s4a = a[0] + a[4], s4b = a[1] + a[5], s4c = a[2] + a[6], s4d = a[3] + a[7];
    float ssum = wave_sum_bcast((s4a + s4b) + (s4c + s4d));

    #pragma unroll
    for (int m = 1; m < 64; m <<= 1)
        peak = fmaxf(peak, __shfl_xor(peak, m, 64));

    const float mean = ssum * (1.0f / (float)NL);
    const float conf = peak / fmaxf(mean, FLOOR_C);

    int idx = 0x7fffffff;
    #pragma unroll
    for (int j = 0; j < 8; ++j)
        if (a[j] == peak) idx = min(idx, lane * 8 + j);
    #pragma unroll
    for (int m = 1; m < 64; m <<= 1)
        idx = min(idx, __shfl_xor(idx, m, 64));

    float4* ar = (float4*)(a_out + (size_t)row * NL + lane * 8);
    float4 o0, o1;
    o0.x = a[0]; o0.y = a[1]; o0.z = a[2]; o0.w = a[3];
    o1.x = a[4]; o1.y = a[5]; o1.z = a[6]; o1.w = a[7];
    ar[0] = o0; ar[1] = o1;

    if (lane == 0) {
        if (sel_out)  sel_out[row]  = (float)idx;
        if (conf_out) conf_out[row] = conf;
    }
}

extern "C" void kernel_launch(void* const* d_in, const int* in_sizes, int n_in,
                              void* d_out, int out_size, void* d_ws, size_t ws_size,
                              hipStream_t stream) {
    const float* c_lex = (const float*)d_in[0];
    const float* W     = (const float*)d_in[1];
    // d_in[2] = a0 (zeros at every reset; recurrence inits a=0 directly)

    // workspace layout: 4 D-partials (33.6 MB) + Whi/Wlo (2.1 MB)
    float* D = (float*)d_ws;
    unsigned short* Whi = (unsigned short*)(D + 4ull * BATCH * NL);
    unsigned short* Wlo = Whi + (size_t)NL * NC;

    float* a_out = (float*)d_out;
    float* sel   = nullptr;
    float* conf  = nullptr;
    const int base = BATCH * NL;
    if (out_size >= base + 2 * BATCH) {        // (a, selected, confidence)
        sel  = a_out + base;
        conf = a_out + base + BATCH;
    } else if (out_size >= base + BATCH) {     // (a, confidence)
        conf = a_out + base;
    }

    // 1) W fp32 -> bf16 hi/lo
    convert_w<<<dim3(512), 256, 0, stream>>>(W, Whi, Wlo);

    // 2) MFMA GEMM, B direct-from-global (no B LDS), splitK=4
    const int kPerSplit = NC / 4;
    gemm_bf16x2<<<dim3(BATCH / TM, NL / TN, 4), 256, 0, stream>>>(
        c_lex, Whi, Wlo, D, kPerSplit);

    // 3) recurrence + selection: 1 row/wave, 4 waves/SIMD, DPP row-sum
    iterate_select<4><<<dim3(BATCH / 4), 256, 0, stream>>>(D, a_out, sel, conf);
}

// Round 14
// 106.884 us; speedup vs baseline: 1.0539x; 1.0539x over previous
//
#include <hip/hip_runtime.h>
#include <hip/hip_bf16.h>

// Problem constants (match reference)
#define BATCH 4096
#define NC    1024   // n_concepts (K)
#define NL    512    // n_lemmas   (N)
#define TSTEPS 50
#define GAMMA_C 0.95f
#define KAPPA_C 0.1f
#define FLOOR_C 1e-6f

typedef __attribute__((ext_vector_type(8))) short short8;  // 8 bf16 = 4 VGPRs
typedef __attribute__((ext_vector_type(4))) float f32x4;   // MFMA C/D frag

// ---------------- split fp32 -> bf16 hi + bf16 lo (RNE both) ----------------
__device__ inline void split_bf16(float x, unsigned short& h, unsigned short& l) {
    unsigned u = __float_as_uint(x);
    unsigned rh = u + 0x7FFFu + ((u >> 16) & 1u);
    h = (unsigned short)(rh >> 16);
    float hf = __uint_as_float((unsigned)h << 16);
    float r = x - hf;
    unsigned v = __float_as_uint(r);
    unsigned rl = v + 0x7FFFu + ((v >> 16) & 1u);
    l = (unsigned short)(rl >> 16);
}

// packed split via v_cvt_pk_bf16_f32 (RNE): ~3 VALU/elem vs ~9 scalar
__device__ __forceinline__ void split2_pk(float x0, float x1,
                                          unsigned& hp, unsigned& lp) {
    union { __hip_bfloat162 b; unsigned u; } ch, cl;
    ch.b = __float22bfloat162_rn(make_float2(x0, x1));
    hp = ch.u;
    const float hf0 = __uint_as_float(hp << 16);
    const float hf1 = __uint_as_float(hp & 0xFFFF0000u);
    cl.b = __float22bfloat162_rn(make_float2(x0 - hf0, x1 - hf1));
    lp = cl.u;
}

// W-only conversion: 512x1024 floats -> hi/lo bf16
__global__ __launch_bounds__(256)
void convert_w(const float* __restrict__ W,
               unsigned short* __restrict__ Whi, unsigned short* __restrict__ Wlo) {
    const int fidx = (blockIdx.x * 256 + threadIdx.x) * 4;
    const float4 v = *(const float4*)(W + fidx);
    ushort4 h4, l4;
    split_bf16(v.x, h4.x, l4.x);
    split_bf16(v.y, h4.y, l4.y);
    split_bf16(v.z, h4.z, l4.z);
    split_bf16(v.w, h4.w, l4.w);
    *(ushort4*)(Whi + fidx) = h4;
    *(ushort4*)(Wlo + fidx) = l4;
}

// ------- full-wave (64-lane) sum, broadcast to all lanes, via DPP ----------
__device__ __forceinline__ float wave_sum_bcast(float x) {
    float f = x;
    f += __int_as_float(__builtin_amdgcn_update_dpp(
            0, __float_as_int(f), 0x111, 0xf, 0xf, true));   // row_shr:1
    f += __int_as_float(__builtin_amdgcn_update_dpp(
            0, __float_as_int(f), 0x112, 0xf, 0xf, true));   // row_shr:2
    f += __int_as_float(__builtin_amdgcn_update_dpp(
            0, __float_as_int(f), 0x114, 0xf, 0xf, true));   // row_shr:4
    f += __int_as_float(__builtin_amdgcn_update_dpp(
            0, __float_as_int(f), 0x118, 0xf, 0xf, true));   // row_shr:8
    f += __int_as_float(__builtin_amdgcn_update_dpp(
            0, __float_as_int(f), 0x142, 0xa, 0xf, true));   // row_bcast:15
    f += __int_as_float(__builtin_amdgcn_update_dpp(
            0, __float_as_int(f), 0x143, 0xc, 0xf, true));   // row_bcast:31
    return __int_as_float(__builtin_amdgcn_readlane(__float_as_int(f), 63));
}

// ------------- MFMA GEMM: D = Ahi*Whi^T + Ahi*Wlo^T + Alo*Whi^T -------------
// r12 structure (best measured: A fp32 pk-split in-kernel, A+B staged in LDS,
// LDT=40) + PREFETCH DISTANCE 2: ping-pong register sets so stage s+2's
// global loads are issued at stage s — ~2 full stages (>=2000 cyc) in flight
// before their vmcnt wait at commit, safely above the ~900 cyc HBM latency
// that distance-1 prefetch only marginally covered.
// Block 128x128, 256 thr = 4 waves (2Mx2N), wave-tile 64x64, GK=32,
// splitK=4 (kPerSplit=256, nst=8 hardcoded) -> grid (32,4,4) = 512 blocks.
#define TM 128
#define TN 128
#define GK 32
#define LDT 40
#define NST 8     // kPerSplit / GK = 256 / 32

__global__ __launch_bounds__(256)
void gemm_bf16x2(const float* __restrict__ A,
                 const unsigned short* __restrict__ Whi, const unsigned short* __restrict__ Wlo,
                 float* __restrict__ Dp) {
    __shared__ unsigned short AsH[TM * LDT];
    __shared__ unsigned short AsL[TM * LDT];
    __shared__ unsigned short BsH[TN * LDT];
    __shared__ unsigned short BsL[TN * LDT];

    const int tid = threadIdx.x;
    const int m0 = blockIdx.x * TM;
    const int n0 = blockIdx.y * TN;
    const int kb = blockIdx.z * (GK * NST);

    const int sr0 = tid >> 1;
    const int kc0 = (tid & 1) * 16;

    const float*          gA  = A   + (size_t)(m0 + sr0) * NC + kb + kc0;
    const unsigned short* gBh = Whi + (size_t)(n0 + sr0) * NC + kb + kc0;
    const unsigned short* gBl = Wlo + (size_t)(n0 + sr0) * NC + kb + kc0;

    unsigned short* wAh = AsH + sr0 * LDT + kc0;
    unsigned short* wAl = AsL + sr0 * LDT + kc0;
    unsigned short* wBh = BsH + sr0 * LDT + kc0;
    unsigned short* wBl = BsL + sr0 * LDT + kc0;

    const int lane = tid & 63;
    const int w    = tid >> 6;
    const int mw   = (w >> 1) * 64;
    const int nw   = (w & 1) * 64;
    const int sr   = lane & 15;
    const int quad = lane >> 4;

    const unsigned short* rAh = AsH + (mw + sr) * LDT + quad * 8;
    const unsigned short* rAl = AsL + (mw + sr) * LDT + quad * 8;
    const unsigned short* rBh = BsH + (nw + sr) * LDT + quad * 8;
    const unsigned short* rBl = BsL + (nw + sr) * LDT + quad * 8;

    f32x4 acc[4][4];
    #pragma unroll
    for (int i = 0; i < 4; ++i)
        #pragma unroll
        for (int j = 0; j < 4; ++j)
            acc[i][j] = (f32x4){0.f, 0.f, 0.f, 0.f};

    // ping-pong prefetch register sets
    float4 pA[2][4];
    short8 pBh[2][2], pBl[2][2];

    #define LOAD_SET(set, kofs)                                   \
        {                                                         \
            pA[set][0]  = *(const float4*)(gA + (kofs));          \
            pA[set][1]  = *(const float4*)(gA + (kofs) + 4);      \
            pA[set][2]  = *(const float4*)(gA + (kofs) + 8);      \
            pA[set][3]  = *(const float4*)(gA + (kofs) + 12);     \
            pBh[set][0] = *(const short8*)(gBh + (kofs));         \
            pBh[set][1] = *(const short8*)(gBh + (kofs) + 8);     \
            pBl[set][0] = *(const short8*)(gBl + (kofs));         \
            pBl[set][1] = *(const short8*)(gBl + (kofs) + 8);     \
        }

    #define COMMIT_SET(set)                                                    \
        {                                                                      \
            unsigned h[8], l[8];                                               \
            split2_pk(pA[set][0].x, pA[set][0].y, h[0], l[0]);                 \
            split2_pk(pA[set][0].z, pA[set][0].w, h[1], l[1]);                 \
            split2_pk(pA[set][1].x, pA[set][1].y, h[2], l[2]);                 \
            split2_pk(pA[set][1].z, pA[set][1].w, h[3], l[3]);                 \
            split2_pk(pA[set][2].x, pA[set][2].y, h[4], l[4]);                 \
            split2_pk(pA[set][2].z, pA[set][2].w, h[5], l[5]);                 \
            split2_pk(pA[set][3].x, pA[set][3].y, h[6], l[6]);                 \
            split2_pk(pA[set][3].z, pA[set][3].w, h[7], l[7]);                 \
            uint4 hv0; hv0.x = h[0]; hv0.y = h[1]; hv0.z = h[2]; hv0.w = h[3]; \
            uint4 hv1; hv1.x = h[4]; hv1.y = h[5]; hv1.z = h[6]; hv1.w = h[7]; \
            uint4 lv0; lv0.x = l[0]; lv0.y = l[1]; lv0.z = l[2]; lv0.w = l[3]; \
            uint4 lv1; lv1.x = l[4]; lv1.y = l[5]; lv1.z = l[6]; lv1.w = l[7]; \
            *(uint4*)wAh       = hv0;                                          \
            *(uint4*)(wAh + 8) = hv1;                                          \
            *(uint4*)wAl       = lv0;                                          \
            *(uint4*)(wAl + 8) = lv1;                                          \
            *(short8*)wBh       = pBh[set][0];                                 \
            *(short8*)(wBh + 8) = pBh[set][1];                                 \
            *(short8*)wBl       = pBl[set][0];                                 \
            *(short8*)(wBl + 8) = pBl[set][1];                                 \
        }

    // prologue: stages 0 and 1 both in flight
    LOAD_SET(0, 0);
    LOAD_SET(1, GK);

    #pragma unroll
    for (int s = 0; s < NST; ++s) {
        const int cur = s & 1;
        COMMIT_SET(cur);            // waits only set[cur]'s loads (issued 2 stages ago)
        __syncthreads();

        if (s + 2 < NST)
            LOAD_SET(cur, (s + 2) * GK);   // reuse freed set; 2 stages to land

        short8 afh[4], afl[4], bfh[4], bfl[4];
        #pragma unroll
        for (int mi = 0; mi < 4; ++mi) {
            afh[mi] = *(const short8*)(rAh + mi * 16 * LDT);
            afl[mi] = *(const short8*)(rAl + mi * 16 * LDT);
        }
        #pragma unroll
        for (int ni = 0; ni < 4; ++ni) {
            bfh[ni] = *(const short8*)(rBh + ni * 16 * LDT);
            bfl[ni] = *(const short8*)(rBl + ni * 16 * LDT);
        }

        // 48 MFMAs: 16 sites x (hi*hi + hi*lo + lo*hi)
        #pragma unroll
        for (int mi = 0; mi < 4; ++mi) {
            #pragma unroll
            for (int ni = 0; ni < 4; ++ni) {
                acc[mi][ni] = __builtin_amdgcn_mfma_f32_16x16x32_bf16(
                    afh[mi], bfh[ni], acc[mi][ni], 0, 0, 0);
                acc[mi][ni] = __builtin_amdgcn_mfma_f32_16x16x32_bf16(
                    afh[mi], bfl[ni], acc[mi][ni], 0, 0, 0);
                acc[mi][ni] = __builtin_amdgcn_mfma_f32_16x16x32_bf16(
                    afl[mi], bfh[ni], acc[mi][ni], 0, 0, 0);
            }
        }
        __syncthreads();
    }

    // epilogue: C/D layout col = lane&15, row = quad*4 + reg  [m89/m91]
    float* Dz = Dp + (size_t)blockIdx.z * BATCH * NL;
    #pragma unroll
    for (int mi = 0; mi < 4; ++mi) {
        #pragma unroll
        for (int ni = 0; ni < 4; ++ni) {
            const int col = n0 + nw + ni * 16 + sr;
            #pragma unroll
            for (int r = 0; r < 4; ++r) {
                const int row = m0 + mw + mi * 16 + quad * 4 + r;
                Dz[(size_t)row * NL + col] = acc[mi][ni][r];
            }
        }
    }
}

// ------ 50-step recurrence + selection: 64 lanes per row, 8 cols/lane -------
template<int SK>
__global__ __launch_bounds__(256)
void iterate_select(const float* __restrict__ Dp,
                    float* __restrict__ a_out,
                    float* __restrict__ sel_out, float* __restrict__ conf_out) {
    const int lane = threadIdx.x & 63;
    const int wave = threadIdx.x >> 6;
    const int row  = blockIdx.x * 4 + wave;

    float d[8];
    {
        float4 v[SK][2];
        #pragma unroll
        for (int s = 0; s < SK; ++s) {
            const float4* ps = (const float4*)(Dp + (size_t)s * BATCH * NL
                                               + (size_t)row * NL + lane * 8);
            v[s][0] = ps[0];
            v[s][1] = ps[1];
        }
        d[0] = v[0][0].x; d[1] = v[0][0].y; d[2] = v[0][0].z; d[3] = v[0][0].w;
        d[4] = v[0][1].x; d[5] = v[0][1].y; d[6] = v[0][1].z; d[7] = v[0][1].w;
        #pragma unroll
        for (int s = 1; s < SK; ++s) {
            d[0] += v[s][0].x; d[1] += v[s][0].y; d[2] += v[s][0].z; d[3] += v[s][0].w;
            d[4] += v[s][1].x; d[5] += v[s][1].y; d[6] += v[s][1].z; d[7] += v[s][1].w;
        }
    }

    float a[8];
    #pragma unroll
    for (int j = 0; j < 8; ++j) a[j] = 0.f;

    const float K1 = 1.0f + KAPPA_C;

    for (int t = 0; t < TSTEPS; ++t) {
        #pragma unroll
        for (int j = 0; j < 8; ++j) a[j] = fmaf(GAMMA_C, a[j], d[j]);

        float t4a = a[0] + a[4], t4b = a[1] + a[5], t4c = a[2] + a[6], t4d = a[3] + a[7];
        float t2a = t4a + t4c, t2b = t4b + t4d;
        const float S = wave_sum_bcast(t2a + t2b);

        const float h = -KAPPA_C * S;
        #pragma unroll
        for (int j = 0; j < 8; ++j) {
            const float v = fmaf(K1, a[j], h);
            a[j] = v > 0.f ? v : 0.f;
        }
    }

    // ---- epilogue (runs once): peak, sum, confidence, first-index argmax ----
    float m4a = fmaxf(a[0], a[4]), m4b = fmaxf(a[1], a[5]);
    float m4c = fmaxf(a[2], a[6]), m4d = fmaxf(a[3], a[7]);
    float peak = fmaxf(fmaxf(m4a, m4b), fmaxf(m4c, m4d));
    float s4a = a[0] + a[4], s4b = a[1] + a[5], s4c = a[2] + a[6], s4d = a[3] + a[7];
    float ssum = wave_sum_bcast((s4a + s4b) + (s4c + s4d));

    #pragma unroll
    for (int m = 1; m < 64; m <<= 1)
        peak = fmaxf(peak, __shfl_xor(peak, m, 64));

    const float mean = ssum * (1.0f / (float)NL);
    const float conf = peak / fmaxf(mean, FLOOR_C);

    int idx = 0x7fffffff;
    #pragma unroll
    for (int j = 0; j < 8; ++j)
        if (a[j] == peak) idx = min(idx, lane * 8 + j);
    #pragma unroll
    for (int m = 1; m < 64; m <<= 1)
        idx = min(idx, __shfl_xor(idx, m, 64));

    float4* ar = (float4*)(a_out + (size_t)row * NL + lane * 8);
    float4 o0, o1;
    o0.x = a[0]; o0.y = a[1]; o0.z = a[2]; o0.w = a[3];
    o1.x = a[4]; o1.y = a[5]; o1.z = a[6]; o1.w = a[7];
    ar[0] = o0; ar[1] = o1;

    if (lane == 0) {
        if (sel_out)  sel_out[row]  = (float)idx;
        if (conf_out) conf_out[row] = conf;
    }
}

extern "C" void kernel_launch(void* const* d_in, const int* in_sizes, int n_in,
                              void* d_out, int out_size, void* d_ws, size_t ws_size,
                              hipStream_t stream) {
    const float* c_lex = (const float*)d_in[0];
    const float* W     = (const float*)d_in[1];
    // d_in[2] = a0 (zeros at every reset; recurrence inits a=0 directly)

    // workspace layout: 4 D-partials (33.6 MB) + Whi/Wlo (2.1 MB)
    float* D = (float*)d_ws;
    unsigned short* Whi = (unsigned short*)(D + 4ull * BATCH * NL);
    unsigned short* Wlo = Whi + (size_t)NL * NC;

    float* a_out = (float*)d_out;
    float* sel   = nullptr;
    float* conf  = nullptr;
    const int base = BATCH * NL;
    if (out_size >= base + 2 * BATCH) {        // (a, selected, confidence)
        sel  = a_out + base;
        conf = a_out + base + BATCH;
    } else if (out_size >= base + BATCH) {     // (a, confidence)
        conf = a_out + base;
    }

    // 1) W fp32 -> bf16 hi/lo
    convert_w<<<dim3(512), 256, 0, stream>>>(W, Whi, Wlo);

    // 2) MFMA GEMM (r12 + distance-2 register prefetch), splitK=4
    gemm_bf16x2<<<dim3(BATCH / TM, NL / TN, 4), 256, 0, stream>>>(
        c_lex, Whi, Wlo, D);

    // 3) recurrence + selection: 1 row/wave, 4 waves/SIMD, DPP row-sum
    iterate_select<4><<<dim3(BATCH / 4), 256, 0, stream>>>(D, a_out, sel, conf);
}